// Round 1
// baseline (30.182 us; speedup 1.0000x reference)
//
#include <hip/hip_runtime.h>

#define SWING_RATIO 0.7f
#define NBLOCKS 4096
#define NTHREADS 256

// Pass 1: per-block partial sums of -w * log(outputs[i, targets[i]])
__global__ __launch_bounds__(NTHREADS) void loss_partial_kernel(
    const float* __restrict__ outputs,
    const int* __restrict__ targets,
    float* __restrict__ partials,
    int N, int C) {
    int tid = blockIdx.x * blockDim.x + threadIdx.x;
    int stride = gridDim.x * blockDim.x;

    float acc = 0.0f;
    for (int i = tid; i < N; i += stride) {
        int t = targets[i];
        float p = outputs[(size_t)i * (size_t)C + (size_t)t];
        float w = (t != 0) ? SWING_RATIO : (1.0f - SWING_RATIO);
        acc -= w * logf(p);
    }

    // wave (64-lane) shuffle reduction
    #pragma unroll
    for (int off = 32; off > 0; off >>= 1)
        acc += __shfl_down(acc, off, 64);

    __shared__ float smem[NTHREADS / 64];
    int lane = threadIdx.x & 63;
    int wid  = threadIdx.x >> 6;
    if (lane == 0) smem[wid] = acc;
    __syncthreads();

    if (threadIdx.x == 0) {
        float s = 0.0f;
        #pragma unroll
        for (int w2 = 0; w2 < NTHREADS / 64; ++w2) s += smem[w2];
        partials[blockIdx.x] = s;   // deterministic: each block owns its slot
    }
}

// Pass 2: single block reduces the partials and writes mean
__global__ __launch_bounds__(NTHREADS) void loss_finalize_kernel(
    const float* __restrict__ partials,
    float* __restrict__ out,
    int nparts, float invN) {
    float acc = 0.0f;
    for (int i = threadIdx.x; i < nparts; i += blockDim.x)
        acc += partials[i];

    #pragma unroll
    for (int off = 32; off > 0; off >>= 1)
        acc += __shfl_down(acc, off, 64);

    __shared__ float smem[NTHREADS / 64];
    int lane = threadIdx.x & 63;
    int wid  = threadIdx.x >> 6;
    if (lane == 0) smem[wid] = acc;
    __syncthreads();

    if (threadIdx.x == 0) {
        float s = 0.0f;
        #pragma unroll
        for (int w2 = 0; w2 < NTHREADS / 64; ++w2) s += smem[w2];
        out[0] = s * invN;
    }
}

extern "C" void kernel_launch(void* const* d_in, const int* in_sizes, int n_in,
                              void* d_out, int out_size, void* d_ws, size_t ws_size,
                              hipStream_t stream) {
    const float* outputs = (const float*)d_in[0];
    const int*   targets = (const int*)d_in[1];
    float*       out     = (float*)d_out;
    float*       partials = (float*)d_ws;   // NBLOCKS floats = 16 KiB

    int N = in_sizes[1];              // number of samples (targets length)
    int C = in_sizes[0] / N;          // classes per row (=128)

    loss_partial_kernel<<<NBLOCKS, NTHREADS, 0, stream>>>(
        outputs, targets, partials, N, C);
    loss_finalize_kernel<<<1, NTHREADS, 0, stream>>>(
        partials, out, NBLOCKS, 1.0f / (float)N);
}

// Round 2
// 27.461 us; speedup vs baseline: 1.0991x; 1.0991x over previous
//
#include <hip/hip_runtime.h>

#define SWING_RATIO 0.7f
#define NTHREADS 256
#define NBLOCKS 1024   // 1024*256 threads * 4 rows/thread = 1,048,576 rows

// Pass 1: each thread gathers 4 rows (independent loads for ILP),
// accumulates w * log(p); per-block partial written deterministically.
__global__ __launch_bounds__(NTHREADS) void loss_partial_kernel(
    const float* __restrict__ outputs,
    const int* __restrict__ targets,
    float* __restrict__ partials,
    int N, int C) {
    int tid = blockIdx.x * blockDim.x + threadIdx.x;
    int nthreads = gridDim.x * blockDim.x;

    float acc = 0.0f;   // accumulates +w*log(p); negated at the end

    int nvec = N >> 2;  // groups of 4 rows
    const int4* t4 = (const int4*)targets;
    for (int v = tid; v < nvec; v += nthreads) {
        int4 t = t4[v];
        size_t base = (size_t)v * 4u * (size_t)C;
        // four independent gathers — compiler schedules all before use
        float p0 = outputs[base                   + (size_t)t.x];
        float p1 = outputs[base +       (size_t)C + (size_t)t.y];
        float p2 = outputs[base + 2u *  (size_t)C + (size_t)t.z];
        float p3 = outputs[base + 3u *  (size_t)C + (size_t)t.w];
        float w0 = (t.x != 0) ? SWING_RATIO : (1.0f - SWING_RATIO);
        float w1 = (t.y != 0) ? SWING_RATIO : (1.0f - SWING_RATIO);
        float w2 = (t.z != 0) ? SWING_RATIO : (1.0f - SWING_RATIO);
        float w3 = (t.w != 0) ? SWING_RATIO : (1.0f - SWING_RATIO);
        acc = fmaf(w0, __logf(p0), acc);
        acc = fmaf(w1, __logf(p1), acc);
        acc = fmaf(w2, __logf(p2), acc);
        acc = fmaf(w3, __logf(p3), acc);
    }
    // tail (N not multiple of 4)
    for (int i = (nvec << 2) + tid; i < N; i += nthreads) {
        int t = targets[i];
        float p = outputs[(size_t)i * (size_t)C + (size_t)t];
        float w = (t != 0) ? SWING_RATIO : (1.0f - SWING_RATIO);
        acc = fmaf(w, __logf(p), acc);
    }

    // wave (64-lane) shuffle reduction
    #pragma unroll
    for (int off = 32; off > 0; off >>= 1)
        acc += __shfl_down(acc, off, 64);

    __shared__ float smem[NTHREADS / 64];
    int lane = threadIdx.x & 63;
    int wid  = threadIdx.x >> 6;
    if (lane == 0) smem[wid] = acc;
    __syncthreads();

    if (threadIdx.x == 0) {
        float s = 0.0f;
        #pragma unroll
        for (int w2s = 0; w2s < NTHREADS / 64; ++w2s) s += smem[w2s];
        partials[blockIdx.x] = s;
    }
}

// Pass 2: single block reduces partials, writes mean of -w*log(p)
__global__ __launch_bounds__(NTHREADS) void loss_finalize_kernel(
    const float* __restrict__ partials,
    float* __restrict__ out,
    int nparts, float invN) {
    float acc = 0.0f;
    for (int i = threadIdx.x; i < nparts; i += blockDim.x)
        acc += partials[i];

    #pragma unroll
    for (int off = 32; off > 0; off >>= 1)
        acc += __shfl_down(acc, off, 64);

    __shared__ float smem[NTHREADS / 64];
    int lane = threadIdx.x & 63;
    int wid  = threadIdx.x >> 6;
    if (lane == 0) smem[wid] = acc;
    __syncthreads();

    if (threadIdx.x == 0) {
        float s = 0.0f;
        #pragma unroll
        for (int w2s = 0; w2s < NTHREADS / 64; ++w2s) s += smem[w2s];
        out[0] = -s * invN;   // negate: acc held +w*log(p)
    }
}

extern "C" void kernel_launch(void* const* d_in, const int* in_sizes, int n_in,
                              void* d_out, int out_size, void* d_ws, size_t ws_size,
                              hipStream_t stream) {
    const float* outputs  = (const float*)d_in[0];
    const int*   targets  = (const int*)d_in[1];
    float*       out      = (float*)d_out;
    float*       partials = (float*)d_ws;   // NBLOCKS floats = 4 KiB

    int N = in_sizes[1];              // number of samples
    int C = in_sizes[0] / N;          // classes per row (=128)

    loss_partial_kernel<<<NBLOCKS, NTHREADS, 0, stream>>>(
        outputs, targets, partials, N, C);
    loss_finalize_kernel<<<1, NTHREADS, 0, stream>>>(
        partials, out, NBLOCKS, 1.0f / (float)N);
}